// Round 9
// baseline (211.833 us; speedup 1.0000x reference)
//
#include <hip/hip_runtime.h>
#include <hip/hip_bf16.h>
#include <math.h>

typedef __attribute__((ext_vector_type(8))) short short8;
typedef __attribute__((ext_vector_type(4))) float floatx4;
typedef __attribute__((ext_vector_type(16))) float floatx16;

#define B_ 8
#define C_ 256
#define N_ 4096
#define LOG2E 1.4426950408889634f
#define VSTRIDE 80    // attn LDS row stride (32 bf16 + pad) — bijective, 16B-aligned
#define XSTRIDE 528   // qkv LDS row stride bytes (256 bf16 + 16B pad)

static __device__ __forceinline__ unsigned short f2bf(float f) {
  union { float f; unsigned int u; } v; v.f = f;
  unsigned int u = v.u;
  u += 0x7FFFu + ((u >> 16) & 1u);   // RNE
  return (unsigned short)(u >> 16);
}
static __device__ __forceinline__ float bf2f(unsigned short h) {
  union { unsigned int u; float f; } v; v.u = ((unsigned int)h) << 16; return v.f;
}
// truncation pack of two positive f32 -> bf16x2 in ONE v_perm_b32
static __device__ __forceinline__ unsigned int pk2(float a, float b) {
  return __builtin_amdgcn_perm(__float_as_uint(b), __float_as_uint(a), 0x07060302u);
}

// ---------------- kernel 0: weight convert + ssq zero ----------------
__global__ void prep_kernel(const float* __restrict__ Wq, const float* __restrict__ Wk,
                            const float* __restrict__ Wv,
                            unsigned short* __restrict__ wqb, unsigned short* __restrict__ wkb,
                            unsigned short* __restrict__ wvb, float* __restrict__ ssq) {
  int t = blockIdx.x * 256 + threadIdx.x;
  if (t < 512) ssq[t] = 0.0f;
  if (t < 8192) { wqb[t] = f2bf(Wq[t]); wkb[t] = f2bf(Wk[t]); }
  int tv = t - 8192;
  if (tv >= 0 && tv < 65536) wvb[tv] = f2bf(Wv[tv]);
}

// ---------------- kernel 1: QKV GEMM, single-pass, LDS-staged x ----------------
// Block: 64 n x all 256 c. Stage: thread t reads x[c=t][n0..n0+63] as float4 (vectorized),
// converts once to bf16, writes LDS [n][c] (scalar u16, 2-way-free banks). Fragments then
// come from ds_read_b128. x read ONCE from HBM (16 KB/block x 512 = 32 MB).
__launch_bounds__(256, 2)
__global__ void qkv_kernel(const float* __restrict__ x,
                           const unsigned short* __restrict__ wqb,
                           const unsigned short* __restrict__ wkb,
                           const unsigned short* __restrict__ wvb,
                           const float* __restrict__ bq, const float* __restrict__ bk,
                           const float* __restrict__ bv,
                           unsigned short* __restrict__ qbf, unsigned short* __restrict__ kbf,
                           unsigned short* __restrict__ vbf, float* __restrict__ ssq) {
  __shared__ __align__(16) char Xt[64 * XSTRIDE];   // [64 n][256 c] bf16 + pad
  int b = blockIdx.x & 7;
  int nblk = blockIdx.x >> 3;
  int tid = threadIdx.x;
  int w = tid >> 6, lane = tid & 63;
  int r = lane & 15, g = lane >> 4;
  int n0 = nblk * 64;

  // ---- stage x tile ----
  const float* xs = x + (((size_t)(b * C_ + tid)) << 12) + n0;
  #pragma unroll
  for (int j = 0; j < 16; ++j) {
    float4 v = *(const float4*)(xs + j * 4);
    *(unsigned short*)(Xt + (j * 4 + 0) * XSTRIDE + tid * 2) = f2bf(v.x);
    *(unsigned short*)(Xt + (j * 4 + 1) * XSTRIDE + tid * 2) = f2bf(v.y);
    *(unsigned short*)(Xt + (j * 4 + 2) * XSTRIDE + tid * 2) = f2bf(v.z);
    *(unsigned short*)(Xt + (j * 4 + 3) * XSTRIDE + tid * 2) = f2bf(v.w);
  }
  __syncthreads();

  // ---- fragments: B[k=c][col=n], lane col = n0 + w*16 + r, k = ks*32 + g*8 + j ----
  short8 xf[8];
  #pragma unroll
  for (int ks = 0; ks < 8; ++ks)
    xf[ks] = *(const short8*)(Xt + (w * 16 + r) * XSTRIDE + (ks * 32 + g * 8) * 2);
  int nw = n0 + w * 16;
  floatx4 zero = {0.f, 0.f, 0.f, 0.f};

  // ---- V: 16 output tiles ----
  #pragma unroll 2
  for (int ot = 0; ot < 16; ++ot) {
    floatx4 acc = zero;
    #pragma unroll
    for (int ks = 0; ks < 8; ++ks) {
      short8 af = *(const short8*)&wvb[(ot * 16 + r) * 256 + ks * 32 + g * 8];
      acc = __builtin_amdgcn_mfma_f32_16x16x32_bf16(af, xf[ks], acc, 0, 0, 0);
    }
    #pragma unroll
    for (int rr = 0; rr < 4; ++rr) {
      int oc = ot * 16 + g * 4 + rr;
      vbf[((size_t)(b * C_ + oc) << 12) + nw + r] = f2bf(acc[rr] + bv[oc]);
    }
  }
  // ---- Q then K (2 tiles each) ----
  #pragma unroll 1
  for (int qk = 0; qk < 2; ++qk) {
    const unsigned short* wb = qk ? wkb : wqb;
    const float* bias = qk ? bk : bq;
    unsigned short* dst = qk ? kbf : qbf;
    int sbase = qk ? 256 : 0;
    #pragma unroll 2
    for (int ot = 0; ot < 2; ++ot) {
      floatx4 acc = zero;
      #pragma unroll
      for (int ks = 0; ks < 8; ++ks) {
        short8 af = *(const short8*)&wb[(ot * 16 + r) * 256 + ks * 32 + g * 8];
        acc = __builtin_amdgcn_mfma_f32_16x16x32_bf16(af, xf[ks], acc, 0, 0, 0);
      }
      #pragma unroll
      for (int rr = 0; rr < 4; ++rr) {
        int oc = ot * 16 + g * 4 + rr;
        float val = acc[rr] + bias[oc];
        dst[(size_t)(b * N_ + nw + r) * 32 + oc] = f2bf(val);
        float s = val * val;               // reduce over the 16 n (lanes r)
        s += __shfl_xor(s, 1);
        s += __shfl_xor(s, 2);
        s += __shfl_xor(s, 4);
        s += __shfl_xor(s, 8);
        if (r == 0) atomicAdd(&ssq[sbase + b * 32 + oc], s);
      }
    }
  }
}

// ---------------- kernel 2: in-place scale of Q,K ----------------
__global__ void scale_kernel(unsigned int* __restrict__ qw, unsigned int* __restrict__ kw,
                             const float* __restrict__ ssq, const float* __restrict__ temp) {
  int tt = blockIdx.x * 256 + threadIdx.x;
  int is_k = tt >> 19;
  int idx = tt & 0x7FFFF;
  unsigned int* ptr = is_k ? kw : qw;
  unsigned int v = ptr[idx];
  int c0 = (idx & 15) * 2;
  int b = idx >> 16;
  float invt = is_k ? 1.0f : LOG2E / (temp[0] + 1e-6f);
  float s0 = ssq[is_k * 256 + b * 32 + c0];
  float s1 = ssq[is_k * 256 + b * 32 + c0 + 1];
  float sc0 = invt / fmaxf(sqrtf(s0), 1e-12f);
  float sc1 = invt / fmaxf(sqrtf(s1), 1e-12f);
  unsigned short lo = f2bf(bf2f((unsigned short)(v & 0xFFFFu)) * sc0);
  unsigned short hi = f2bf(bf2f((unsigned short)(v >> 16)) * sc1);
  ptr[idx] = ((unsigned int)hi << 16) | lo;
}

// ---------------- kernel 3: 32x32-MFMA attention, in-register P ----------------
// As round 8, plus: constant shift -2*log2e folded into the QK MFMA C-init (no subs),
// bf16 pack via single v_perm_b32.
__launch_bounds__(512, 2)
__global__ void attn_kernel(const unsigned short* __restrict__ qbf,
                            const unsigned short* __restrict__ kbf,
                            const unsigned short* __restrict__ vbf,
                            const float* __restrict__ x, const float* __restrict__ gamma,
                            float* __restrict__ out) {
  __shared__ __align__(16) char Vt[2][256 * VSTRIDE];   // [buf][256 cv][32 n + pad]
  __shared__ __align__(16) char Kt[2][32 * VSTRIDE];    // [buf][32 n][32 ch + pad]
  int b = blockIdx.x & 7, mblk = blockIdx.x >> 3;       // mblk in [0,32)
  int tid = threadIdx.x;
  int w = tid >> 6, lane = tid & 63, c = lane & 31, h = lane >> 5;
  int ms = w & 3, cvh = w >> 2;
  const unsigned short* qb = qbf + (size_t)b * N_ * 32;
  const unsigned short* kb = kbf + (size_t)b * N_ * 32;
  const unsigned short* vb = vbf + (size_t)b * C_ * N_;
  int mrow = mblk * 128 + ms * 32 + c;                  // this lane's global m (column)
  short8 qf0 = *(const short8*)&qb[mrow * 32 + h * 8];
  short8 qf1 = *(const short8*)&qb[mrow * 32 + 16 + h * 8];
  int tdiag = mblk * 4 + ms;

  // staging: V 16KB by all 512 thr (32B each), K 2KB by tid<128 (16B each)
  int vrow = tid >> 1, vhalf = tid & 1;
  const unsigned short* vsrc_base = vb + (size_t)vrow * N_ + vhalf * 16;
  int krow = tid >> 2, kq = tid & 3;
  const unsigned short* ksrc_base = kb + (size_t)krow * 32 + kq * 8;
  int vwr0 = vrow * VSTRIDE + vhalf * 32;
  int vwr1 = vwr0 + 16;
  int kwr = krow * VSTRIDE + kq * 16;

  floatx16 zero16 = {0,0,0,0,0,0,0,0,0,0,0,0,0,0,0,0};
  floatx16 minit;                                        // C-init = -2*log2e (softmax shift)
  #pragma unroll
  for (int i = 0; i < 16; ++i) minit[i] = -2.0f * LOG2E;
  floatx16 acc[4] = {zero16, zero16, zero16, zero16};    // [cvt] D[cv 32][m 32]
  float Lp = 0.0f;
  short8 sv0, sv1, sk;

  auto issue = [&](int t) {
    const unsigned short* vs = vsrc_base + t * 32;
    sv0 = *(const short8*)vs;
    sv1 = *(const short8*)(vs + 8);
    if (tid < 128) sk = *(const short8*)(ksrc_base + (size_t)t * 1024);
  };
  auto commit = [&](int buf) {
    *(short8*)(Vt[buf] + vwr0) = sv0;
    *(short8*)(Vt[buf] + vwr1) = sv1;
    if (tid < 128) *(short8*)(Kt[buf] + kwr) = sk;
  };
  auto compute = [&](int t, int buf) {
    const char* Kb = Kt[buf];
    const char* Vb = Vt[buf];
    short8 kf0 = *(const short8*)(Kb + c * VSTRIDE + h * 16);
    short8 kf1 = *(const short8*)(Kb + c * VSTRIDE + 32 + h * 16);
    floatx16 s = __builtin_amdgcn_mfma_f32_32x32x16_bf16(kf0, qf0, minit, 0, 0, 0);
    s = __builtin_amdgcn_mfma_f32_32x32x16_bf16(kf1, qf1, s, 0, 0, 0);
    if (t == tdiag && ((c >> 2) & 1) == h)              // +I where global n == m
      s[(c & 3) | ((c >> 3) << 2)] += LOG2E;
    float p[16];
    float ls = 0.0f;
    #pragma unroll
    for (int i = 0; i < 16; ++i) {
      p[i] = __builtin_amdgcn_exp2f(s[i]);
      ls += p[i];
    }
    Lp += ls;
    #pragma unroll
    for (int t16 = 0; t16 < 2; ++t16) {
      unsigned int q0 = pk2(p[8*t16+0], p[8*t16+1]);
      unsigned int q1 = pk2(p[8*t16+2], p[8*t16+3]);
      unsigned int q2 = pk2(p[8*t16+4], p[8*t16+5]);
      unsigned int q3 = pk2(p[8*t16+6], p[8*t16+7]);
      // swap(vdst,vsrc): vdst[0:31] <-> vsrc[32:63]
      asm volatile("v_permlane32_swap_b32 %0, %1" : "+v"(q2), "+v"(q0));
      asm volatile("v_permlane32_swap_b32 %0, %1" : "+v"(q3), "+v"(q1));
      union { unsigned int u[4]; short8 s8; } bf;
      bf.u[0] = q0; bf.u[1] = q1; bf.u[2] = q2; bf.u[3] = q3;
      #pragma unroll
      for (int cvt = 0; cvt < 4; ++cvt) {
        int R = cvh * 128 + cvt * 32 + c;
        short8 af = *(const short8*)(Vb + R * VSTRIDE + t16 * 32 + h * 16);
        acc[cvt] = __builtin_amdgcn_mfma_f32_32x32x16_bf16(af, bf.s8, acc[cvt], 0, 0, 0);
      }
    }
  };

  issue(0); commit(0); __syncthreads();
  issue(1);
  #pragma unroll 1
  for (int t = 0; t < 128; ++t) {
    int cur = t & 1;
    compute(t, cur);
    if (t + 1 < 128) commit(cur ^ 1);
    __syncthreads();
    if (t + 2 < 128) issue(t + 2);
  }

  // denominator: lane holds half the n-sum for column m; partner (lane^32) has the rest
  Lp += __shfl_xor(Lp, 32);
  float linv = 1.0f / Lp;
  float gam = gamma[0];
  #pragma unroll
  for (int cvt = 0; cvt < 4; ++cvt)
    #pragma unroll
    for (int i = 0; i < 16; ++i) {
      int cv = cvh * 128 + cvt * 32 + (i & 3) + 8 * (i >> 2) + 4 * h;
      size_t idx = ((size_t)(b * C_ + cv) << 12) + mrow;
      out[idx] = gam * acc[cvt][i] * linv + x[idx];
    }
}

extern "C" void kernel_launch(void* const* d_in, const int* in_sizes, int n_in,
                              void* d_out, int out_size, void* d_ws, size_t ws_size,
                              hipStream_t stream) {
  (void)in_sizes; (void)n_in; (void)out_size; (void)ws_size;
  const float* x    = (const float*)d_in[0];
  const float* Wq   = (const float*)d_in[1];
  const float* bq   = (const float*)d_in[2];
  const float* Wk   = (const float*)d_in[3];
  const float* bk   = (const float*)d_in[4];
  const float* Wv   = (const float*)d_in[5];
  const float* bv   = (const float*)d_in[6];
  const float* gam  = (const float*)d_in[7];
  const float* temp = (const float*)d_in[8];
  float* out = (float*)d_out;

  char* ws = (char*)d_ws;
  unsigned short* vbf = (unsigned short*)ws;                       // 16 MB
  unsigned short* qbf = (unsigned short*)(ws + (16u << 20));       // 2 MB
  unsigned short* kbf = (unsigned short*)(ws + (18u << 20));       // 2 MB
  unsigned short* wqb = (unsigned short*)(ws + (20u << 20));       // 16 KB
  unsigned short* wkb = wqb + 8192;                                // 16 KB
  unsigned short* wvb = wkb + 8192;                                // 128 KB
  float* ssq = (float*)(wvb + 65536);                              // 2 KB

  prep_kernel<<<dim3(288), dim3(256), 0, stream>>>(Wq, Wk, Wv, wqb, wkb, wvb, ssq);
  qkv_kernel<<<dim3(512), dim3(256), 0, stream>>>(x, wqb, wkb, wvb, bq, bk, bv, qbf, kbf, vbf, ssq);
  scale_kernel<<<dim3(4096), dim3(256), 0, stream>>>((unsigned int*)qbf, (unsigned int*)kbf, ssq, temp);
  attn_kernel<<<dim3(256), dim3(512), 0, stream>>>(qbf, kbf, vbf, x, gam, out);
}